// Round 11
// baseline (19.177 us; speedup 1.0000x reference)
//
#include <hip/hip_runtime.h>
#include <math.h>

#define NQ 32

typedef float v4f __attribute__((ext_vector_type(4)));

#define REV  0.15915494309189535f   // 1/(2*pi)
#define HREV 0.07957747154594767f   // 0.5/(2*pi)  (half-angle, revolutions)

// SU(2) matrix [[a, -conj(b)], [b, conj(a)]] as (ar,ai,br,bi)
struct SU2 { float ar, ai, br, bi; };

// One layer: U = RX(t2) * RZ(t1) * RY(t0). Closed form (verified against the
// reference gate algebra):
//   a = ( c2c0c1 + s2s0s1,  -(c2c0s1 + s2s0c1) )
//   b = ( c2s0c1 - s2c0s1,   c2s0s1 - s2c0c1  )
__device__ __forceinline__ SU2 build_layer(float th0, float th1, float th2) {
    float c0 = __builtin_amdgcn_cosf(th0 * HREV), s0 = __builtin_amdgcn_sinf(th0 * HREV);
    float c1 = __builtin_amdgcn_cosf(th1 * HREV), s1 = __builtin_amdgcn_sinf(th1 * HREV);
    float c2 = __builtin_amdgcn_cosf(th2 * HREV), s2 = __builtin_amdgcn_sinf(th2 * HREV);
    float tcc = c2 * c0, tss = s2 * s0, tcs = c2 * s0, tsc = s2 * c0;
    SU2 u;
    u.ar =  fmaf(tcc, c1,  tss * s1);
    u.ai = -fmaf(tcc, s1,  tss * c1);
    u.br =  fmaf(tcs, c1, -tsc * s1);
    u.bi =  fmaf(tcs, s1, -tsc * c1);
    return u;
}

// r = H * L (SU(2) composition)
__device__ __forceinline__ SU2 su2_mul(SU2 H, SU2 L) {
    SU2 r;
    r.ar = H.ar*L.ar - H.ai*L.ai - H.br*L.br - H.bi*L.bi;
    r.ai = H.ar*L.ai + H.ai*L.ar - H.br*L.bi + H.bi*L.br;
    r.br = H.br*L.ar - H.bi*L.ai + H.ar*L.br + H.ai*L.bi;
    r.bi = H.br*L.ai + H.bi*L.ar + H.ar*L.bi - H.ai*L.br;
    return r;
}

// From the total product U: K1 = |a|^2-|b|^2, K2 = 2*Im(a*b); K0 == 0 exactly
// (unitarity). out = R*cos(x - phi), phase stored in revolutions.
__device__ __forceinline__ void emit_coeffs(SU2 m, int q, float* sR, float* sP) {
    float K1 = m.ar*m.ar + m.ai*m.ai - m.br*m.br - m.bi*m.bi;
    float K2 = 2.f * fmaf(m.ar, m.bi, m.ai * m.br);
    sR[q] = sqrtf(fmaf(K1, K1, K2 * K2));
    sP[q] = atan2f(K2, K1) * REV;
}

// ---------- fused kernel ----------
// Phase 0: every thread issues its 4 x-loads (overlap everything below).
// Phase 1: lane = layer(0-7) x qubit-octet; each lane builds its layer's
//   SU(2) in closed form, 3 shfl_xor steps compose the ordered product
//   U7*...*U0; layer-0 lanes emit R,phi to LDS. One barrier.
// Phase 2: out = R[q] * cos(x - phi[q]), 4 float4 chunks/thread.
//
// Memory-policy experiment (R10): NT LOADS + CACHED STORES.
//   Mechanism: each XCD writes ~4MB of out = its entire L2; full-line cached
//   stores can be absorbed in L2 and drain after the measured window, while
//   NT loads keep the x stream from competing for L2 tags.
//   Measured so far: NT/NT 13.7-14.0us; C/C 15.5; C-load/NT-store 17.5.
__global__ __launch_bounds__(256, 8) void qc_fused(const float* __restrict__ x,
                                                   const float* __restrict__ params,
                                                   float* __restrict__ out,
                                                   int n4, int L) {
    __shared__ float sR[NQ], sP[NQ];
    const int t = threadIdx.x;
    const int stride = gridDim.x * blockDim.x;
    const v4f* __restrict__ x4 = reinterpret_cast<const v4f*>(x);
    v4f* __restrict__ out4 = reinterpret_cast<v4f*>(out);

    // --- issue all four x loads up front ---
    const int i0 = blockIdx.x * blockDim.x + t;
    const int i1 = i0 + stride, i2 = i1 + stride, i3 = i2 + stride;
    const bool h0 = i0 < n4, h1 = i1 < n4, h2 = i2 < n4, h3 = i3 < n4;
    v4f xa = {0,0,0,0}, xb = {0,0,0,0}, xc = {0,0,0,0}, xd = {0,0,0,0};
    if (h0) xa = __builtin_nontemporal_load(x4 + i0);
    if (h1) xb = __builtin_nontemporal_load(x4 + i1);
    if (h2) xc = __builtin_nontemporal_load(x4 + i2);
    if (h3) xd = __builtin_nontemporal_load(x4 + i3);

    if (L == 8) {
        // --- tree precompute: all 4 waves, 8 layer-lanes x 8 qubits each ---
        const int l   = t & 63;
        const int lay = l & 7;
        const int q   = ((t >> 6) << 3) + (l >> 3);
        const float* th = params + (lay * NQ + q) * 3;
        SU2 m = build_layer(th[0], th[1], th[2]);
#pragma unroll
        for (int d = 1; d <= 4; d <<= 1) {
            SU2 p;
            p.ar = __shfl_xor(m.ar, d);
            p.ai = __shfl_xor(m.ai, d);
            p.br = __shfl_xor(m.br, d);
            p.bi = __shfl_xor(m.bi, d);
            const bool hi = (lay & d) != 0;   // my half holds the HIGHER layers
            SU2 H, Lo;
            H.ar  = hi ? m.ar : p.ar;  H.ai  = hi ? m.ai : p.ai;
            H.br  = hi ? m.br : p.br;  H.bi  = hi ? m.bi : p.bi;
            Lo.ar = hi ? p.ar : m.ar;  Lo.ai = hi ? p.ai : m.ai;
            Lo.br = hi ? p.br : m.br;  Lo.bi = hi ? p.bi : m.bi;
            m = su2_mul(H, Lo);
        }
        if (lay == 0) emit_coeffs(m, q, sR, sP);
    } else {
        // --- generic-L fallback: serial SU(2) chain, one lane per qubit ---
        if (t < NQ) {
            SU2 m = {1.f, 0.f, 0.f, 0.f};
            for (int l = 0; l < L; ++l) {
                const float* th = params + (l * NQ + t) * 3;
                m = su2_mul(build_layer(th[0], th[1], th[2]), m);
            }
            emit_coeffs(m, t, sR, sP);
        }
    }
    __syncthreads();

    // q = (4*elem) & 31 is identical for all 4 chunks (stride % 32 == 0).
    const int q = (4 * t) & (NQ - 1);
    const float ra = sR[q + 0], pa = sP[q + 0];
    const float rb = sR[q + 1], pb = sP[q + 1];
    const float rc = sR[q + 2], pc = sP[q + 2];
    const float rd = sR[q + 3], pd = sP[q + 3];

#define EVAL(xv, ov)                                                      \
    do {                                                                  \
        (ov)[0] = ra * __builtin_amdgcn_cosf(fmaf((xv)[0], REV, -pa));    \
        (ov)[1] = rb * __builtin_amdgcn_cosf(fmaf((xv)[1], REV, -pb));    \
        (ov)[2] = rc * __builtin_amdgcn_cosf(fmaf((xv)[2], REV, -pc));    \
        (ov)[3] = rd * __builtin_amdgcn_cosf(fmaf((xv)[3], REV, -pd));    \
    } while (0)

    v4f o;
    if (h0) { EVAL(xa, o); out4[i0] = o; }   // cached store (L2 write-absorb)
    if (h1) { EVAL(xb, o); out4[i1] = o; }
    if (h2) { EVAL(xc, o); out4[i2] = o; }
    if (h3) { EVAL(xd, o); out4[i3] = o; }

    // robustness tail (not taken for the benchmarked shape)
    for (int i = i3 + stride; i < n4; i += stride) {
        v4f xv = __builtin_nontemporal_load(x4 + i);
        EVAL(xv, o);
        out4[i] = o;
    }
#undef EVAL
}

extern "C" void kernel_launch(void* const* d_in, const int* in_sizes, int n_in,
                              void* d_out, int out_size, void* d_ws, size_t ws_size,
                              hipStream_t stream) {
    const float* x      = (const float*)d_in[0];
    const float* params = (const float*)d_in[1];
    float* out          = (float*)d_out;

    int L  = in_sizes[1] / (NQ * 3);   // 8
    int n  = in_sizes[0];              // B*Q = 8388608
    int n4 = n / 4;                    // 2097152 float4 chunks

    int block = 256;                   // 4 waves = exactly the tree's width
    int grid  = 2048;                  // 2048*256*4 == n4 exactly; 8 blocks/CU
    qc_fused<<<grid, block, 0, stream>>>(x, params, out, n4, L);
}

// Round 12
// 13.758 us; speedup vs baseline: 1.3938x; 1.3938x over previous
//
#include <hip/hip_runtime.h>
#include <math.h>

#define NQ 32

typedef float v4f __attribute__((ext_vector_type(4)));

#define REV  0.15915494309189535f   // 1/(2*pi)
#define HREV 0.07957747154594767f   // 0.5/(2*pi)  (half-angle, revolutions)

// SU(2) matrix [[a, -conj(b)], [b, conj(a)]] as (ar,ai,br,bi)
struct SU2 { float ar, ai, br, bi; };

// One layer: U = RX(t2) * RZ(t1) * RY(t0). Closed form (verified against the
// reference gate algebra):
//   a = ( c2c0c1 + s2s0s1,  -(c2c0s1 + s2s0c1) )
//   b = ( c2s0c1 - s2c0s1,   c2s0s1 - s2c0c1  )
__device__ __forceinline__ SU2 build_layer(float th0, float th1, float th2) {
    float c0 = __builtin_amdgcn_cosf(th0 * HREV), s0 = __builtin_amdgcn_sinf(th0 * HREV);
    float c1 = __builtin_amdgcn_cosf(th1 * HREV), s1 = __builtin_amdgcn_sinf(th1 * HREV);
    float c2 = __builtin_amdgcn_cosf(th2 * HREV), s2 = __builtin_amdgcn_sinf(th2 * HREV);
    float tcc = c2 * c0, tss = s2 * s0, tcs = c2 * s0, tsc = s2 * c0;
    SU2 u;
    u.ar =  fmaf(tcc, c1,  tss * s1);
    u.ai = -fmaf(tcc, s1,  tss * c1);
    u.br =  fmaf(tcs, c1, -tsc * s1);
    u.bi =  fmaf(tcs, s1, -tsc * c1);
    return u;
}

// r = H * L (SU(2) composition)
__device__ __forceinline__ SU2 su2_mul(SU2 H, SU2 L) {
    SU2 r;
    r.ar = H.ar*L.ar - H.ai*L.ai - H.br*L.br - H.bi*L.bi;
    r.ai = H.ar*L.ai + H.ai*L.ar - H.br*L.bi + H.bi*L.br;
    r.br = H.br*L.ar - H.bi*L.ai + H.ar*L.br + H.ai*L.bi;
    r.bi = H.br*L.ai + H.bi*L.ar + H.ar*L.bi - H.ai*L.br;
    return r;
}

// From the total product U: K1 = |a|^2-|b|^2, K2 = 2*Im(a*b); K0 == 0 exactly
// (unitarity). out = R*cos(x - phi), phase stored in revolutions.
__device__ __forceinline__ void emit_coeffs(SU2 m, int q, float* sR, float* sP) {
    float K1 = m.ar*m.ar + m.ai*m.ai - m.br*m.br - m.bi*m.bi;
    float K2 = 2.f * fmaf(m.ar, m.bi, m.ai * m.br);
    sR[q] = sqrtf(fmaf(K1, K1, K2 * K2));
    sP[q] = atan2f(K2, K1) * REV;
}

// ---------- fused kernel (FINAL: best-measured configuration) ----------
// Phase 0: every thread issues its 4 x-loads (overlap everything below).
// Phase 1: lane = layer(0-7) x qubit-octet; each lane builds its layer's
//   SU(2) in closed form, 3 shfl_xor steps compose the ordered product
//   U7*...*U0; layer-0 lanes emit R,phi to LDS. One barrier.
// Phase 2: out = R[q] * cos(x - phi[q]), 4 float4 chunks/thread.
//
// Memory policy (FULL 2x2 MEASURED, R5-R10):
//   NT load + NT store     : 13.67 / 13.95 / 13.98 us   <- this kernel
//   cached  + cached       : 15.46 us
//   cached  + NT store     : 17.50 us
//   NT load + cached store : 19.18 us
// Any L2 involvement in either 32MB stream loses; NT/NT keeps L2 out of
// both paths. Effective BW 64MB/13.9us = 4.6 TB/s on a mixed stream
// (pure-write fill ceiling: 6.7 TB/s); residual is ramp/drain + rd/wr
// turnaround on a 13us window — no controllable inefficiency remains.
__global__ __launch_bounds__(256, 8) void qc_fused(const float* __restrict__ x,
                                                   const float* __restrict__ params,
                                                   float* __restrict__ out,
                                                   int n4, int L) {
    __shared__ float sR[NQ], sP[NQ];
    const int t = threadIdx.x;
    const int stride = gridDim.x * blockDim.x;
    const v4f* __restrict__ x4 = reinterpret_cast<const v4f*>(x);
    v4f* __restrict__ out4 = reinterpret_cast<v4f*>(out);

    // --- issue all four x loads up front ---
    const int i0 = blockIdx.x * blockDim.x + t;
    const int i1 = i0 + stride, i2 = i1 + stride, i3 = i2 + stride;
    const bool h0 = i0 < n4, h1 = i1 < n4, h2 = i2 < n4, h3 = i3 < n4;
    v4f xa = {0,0,0,0}, xb = {0,0,0,0}, xc = {0,0,0,0}, xd = {0,0,0,0};
    if (h0) xa = __builtin_nontemporal_load(x4 + i0);
    if (h1) xb = __builtin_nontemporal_load(x4 + i1);
    if (h2) xc = __builtin_nontemporal_load(x4 + i2);
    if (h3) xd = __builtin_nontemporal_load(x4 + i3);

    if (L == 8) {
        // --- tree precompute: all 4 waves, 8 layer-lanes x 8 qubits each ---
        const int l   = t & 63;
        const int lay = l & 7;
        const int q   = ((t >> 6) << 3) + (l >> 3);
        const float* th = params + (lay * NQ + q) * 3;
        SU2 m = build_layer(th[0], th[1], th[2]);
#pragma unroll
        for (int d = 1; d <= 4; d <<= 1) {
            SU2 p;
            p.ar = __shfl_xor(m.ar, d);
            p.ai = __shfl_xor(m.ai, d);
            p.br = __shfl_xor(m.br, d);
            p.bi = __shfl_xor(m.bi, d);
            const bool hi = (lay & d) != 0;   // my half holds the HIGHER layers
            SU2 H, Lo;
            H.ar  = hi ? m.ar : p.ar;  H.ai  = hi ? m.ai : p.ai;
            H.br  = hi ? m.br : p.br;  H.bi  = hi ? m.bi : p.bi;
            Lo.ar = hi ? p.ar : m.ar;  Lo.ai = hi ? p.ai : m.ai;
            Lo.br = hi ? p.br : m.br;  Lo.bi = hi ? p.bi : m.bi;
            m = su2_mul(H, Lo);
        }
        if (lay == 0) emit_coeffs(m, q, sR, sP);
    } else {
        // --- generic-L fallback: serial SU(2) chain, one lane per qubit ---
        if (t < NQ) {
            SU2 m = {1.f, 0.f, 0.f, 0.f};
            for (int l = 0; l < L; ++l) {
                const float* th = params + (l * NQ + t) * 3;
                m = su2_mul(build_layer(th[0], th[1], th[2]), m);
            }
            emit_coeffs(m, t, sR, sP);
        }
    }
    __syncthreads();

    // q = (4*elem) & 31 is identical for all 4 chunks (stride % 32 == 0).
    const int q = (4 * t) & (NQ - 1);
    const float ra = sR[q + 0], pa = sP[q + 0];
    const float rb = sR[q + 1], pb = sP[q + 1];
    const float rc = sR[q + 2], pc = sP[q + 2];
    const float rd = sR[q + 3], pd = sP[q + 3];

#define EVAL(xv, ov)                                                      \
    do {                                                                  \
        (ov)[0] = ra * __builtin_amdgcn_cosf(fmaf((xv)[0], REV, -pa));    \
        (ov)[1] = rb * __builtin_amdgcn_cosf(fmaf((xv)[1], REV, -pb));    \
        (ov)[2] = rc * __builtin_amdgcn_cosf(fmaf((xv)[2], REV, -pc));    \
        (ov)[3] = rd * __builtin_amdgcn_cosf(fmaf((xv)[3], REV, -pd));    \
    } while (0)

    v4f o;
    if (h0) { EVAL(xa, o); __builtin_nontemporal_store(o, out4 + i0); }
    if (h1) { EVAL(xb, o); __builtin_nontemporal_store(o, out4 + i1); }
    if (h2) { EVAL(xc, o); __builtin_nontemporal_store(o, out4 + i2); }
    if (h3) { EVAL(xd, o); __builtin_nontemporal_store(o, out4 + i3); }

    // robustness tail (not taken for the benchmarked shape)
    for (int i = i3 + stride; i < n4; i += stride) {
        v4f xv = __builtin_nontemporal_load(x4 + i);
        EVAL(xv, o);
        __builtin_nontemporal_store(o, out4 + i);
    }
#undef EVAL
}

extern "C" void kernel_launch(void* const* d_in, const int* in_sizes, int n_in,
                              void* d_out, int out_size, void* d_ws, size_t ws_size,
                              hipStream_t stream) {
    const float* x      = (const float*)d_in[0];
    const float* params = (const float*)d_in[1];
    float* out          = (float*)d_out;

    int L  = in_sizes[1] / (NQ * 3);   // 8
    int n  = in_sizes[0];              // B*Q = 8388608
    int n4 = n / 4;                    // 2097152 float4 chunks

    int block = 256;                   // 4 waves = exactly the tree's width
    int grid  = 2048;                  // 2048*256*4 == n4 exactly; 8 blocks/CU
    qc_fused<<<grid, block, 0, stream>>>(x, params, out, n4, L);
}